// Round 14
// baseline (219.120 us; speedup 1.0000x reference)
//
#include <hip/hip_runtime.h>

#define NTOT 262144
#define BN   64
#define NT   512
#define SXS  296     // sX row stride in shorts (288 + 8 pad; conflict-free b128 reads)
#define VTS  36      // V^T / V_h^T row stride in shorts (32 + 4 pad)

typedef __attribute__((ext_vector_type(8))) short bf16x8;
typedef __attribute__((ext_vector_type(4))) float f32x4;

static __device__ __forceinline__ unsigned short f2b(float x) {
    union { float f; unsigned u; } c; c.f = x;
    unsigned r = c.u + 0x7FFFu + ((c.u >> 16) & 1u);   // RNE
    return (unsigned short)(r >> 16);
}
static __device__ __forceinline__ bf16x8 cvt8(const float* p) {
    float4 x = *(const float4*)p, y = *(const float4*)(p + 4);
    bf16x8 r;
    r[0] = (short)f2b(x.x); r[1] = (short)f2b(x.y); r[2] = (short)f2b(x.z); r[3] = (short)f2b(x.w);
    r[4] = (short)f2b(y.x); r[5] = (short)f2b(y.y); r[6] = (short)f2b(y.z); r[7] = (short)f2b(y.w);
    return r;
}
static __device__ __forceinline__ void glds16(const unsigned short* g, void* l) {
    __builtin_amdgcn_global_load_lds(
        (const __attribute__((address_space(1))) void*)g,
        (__attribute__((address_space(3))) void*)l, 16, 0, 0);
}

// Pack W_m_w -> bf16, 36 quarter-chunks [64 cols][32 k] (qc = ks*4 + q),
// XOR-swizzled on k (kk ^= ((ol>>1)&3)<<3). W_g_w -> bf16 k-chunked at 73728.
__global__ void pack_w(const float* __restrict__ Wmw, const float* __restrict__ Wgw,
                       unsigned short* __restrict__ wp) {
    int t = blockIdx.x * 256 + threadIdx.x;
    if (t < 73728) {
        int o = t / 288, k = t % 288;
        int ks = k >> 5, kk = k & 31, q = o >> 6, ol = o & 63;
        int kks = kk ^ (((ol >> 1) & 3) << 3);
        wp[(ks * 4 + q) * 2048 + ol * 32 + kks] = f2b(Wmw[t]);
    } else if (t < 81920) {
        int j = t - 73728;
        int o = j >> 8, k = j & 255;
        wp[73728 + (k >> 5) * 1024 + o * 32 + (k & 31)] = f2b(Wgw[j]);
    }
}

// BN=64 / 8-wave design: two independent 32-node groups (g = w>>2) amortize the
// per-block serial phase chain over 2x the nodes. K-loop barrier-free: wave wg
// of group g stages AND reads only cols wg*16+[0,16) of each quarter-chunk into
// a group-private 3-slot buffer (strictly wave-private -> no cross-wave hazard).
// Counted vmcnt(2) steady (never 0 mid-loop). Gate in registers. s_dash stored
// direct (safe at 2 blocks/CU: r6 exact WRITE; amplifies only at >=3, r7).
// LDS 76,288 B -> 2 blocks/CU (16 waves).
template<int USE_WS>
__global__ __launch_bounds__(NT, 2)
void gvp_main(const float* __restrict__ s, const float* __restrict__ V,
              const float* __restrict__ Wh, const float* __restrict__ Wmu,
              const float* __restrict__ Wmw, const float* __restrict__ Wmb,
              const float* __restrict__ Wgw, const float* __restrict__ Wgb,
              const unsigned short* __restrict__ wpack,
              float* __restrict__ out)
{
    // sX  bf16 [64][296] 37,888 B: s | s_h -> sigmoid(s_m) -> V_dash f32 [64][96]
    // sWb [2 grp][3 slot][2048] 24,576 B: W quarter-chunk rotation (wave-private slices)
    // sVT bf16 [192][36] 13,824 B: V^T (c-major, per group), then V_h^T
    __shared__ __attribute__((aligned(16))) unsigned short sX[BN * SXS];
    __shared__ __attribute__((aligned(16))) unsigned short sWb[2 * 3 * 2048];
    __shared__ __attribute__((aligned(16))) unsigned short sVT[192 * VTS];

    const int t  = threadIdx.x;
    const int w  = t >> 6, l = t & 63;
    const int fr = l & 15, fq = l >> 4;
    const int n0 = blockIdx.x * BN;
    const int g  = w >> 2, wg = w & 3;     // group, wave-in-group
    const int half = wg & 1, oh = wg >> 1; // phase A/D/gate mapping (per group)

    // ---------------- prologue: issue W quarters 0,1,2 (async, wave-private) ---
    if (USE_WS) {
        #pragma unroll
        for (int c = 0; c < 3; ++c)
            glds16(wpack + c * 2048 + wg * 512 + l * 8,
                   &sWb[(g * 3 + c) * 2048 + wg * 512]);
    }

    // ---------------- stage s -> sX (bf16), V -> sVT (c-major, per group) ------
    #pragma unroll
    for (int i = 0; i < 8; ++i) {
        int n = i * 8 + w;
        float4 x4 = *(const float4*)&s[(size_t)(n0 + n) * 256 + 4 * l];
        ushort4 h4; h4.x = f2b(x4.x); h4.y = f2b(x4.y); h4.z = f2b(x4.z); h4.w = f2b(x4.w);
        *(ushort4*)&sX[n * SXS + 4 * l] = h4;
    }
    {   // thread t -> node n = t>>3 (0..63), v-quad vq = t&7
        int n = t >> 3, vq = t & 7;
        int gg = n >> 5, nn = n & 31;
        const float* p = &V[(size_t)(n0 + n) * 96 + vq * 12];
        float4 q0 = *(const float4*)(p);
        float4 q1 = *(const float4*)(p + 4);
        float4 q2 = *(const float4*)(p + 8);
        ushort4 c0 = { f2b(q0.x), f2b(q0.w), f2b(q1.z), f2b(q2.y) };   // c=0
        ushort4 c1 = { f2b(q0.y), f2b(q1.x), f2b(q1.w), f2b(q2.z) };   // c=1
        ushort4 c2 = { f2b(q0.z), f2b(q1.y), f2b(q2.x), f2b(q2.w) };   // c=2
        *(ushort4*)&sVT[(gg * 96 + 0 * 32 + nn) * VTS + vq * 4] = c0;
        *(ushort4*)&sVT[(gg * 96 + 1 * 32 + nn) * VTS + vq * 4] = c1;
        *(ushort4*)&sVT[(gg * 96 + 2 * 32 + nn) * VTS + vq * 4] = c2;
    }
    if (!USE_WS) {   // fallback: cvt-stage quarters 0,1,2 (ks=0, q=c), own slice
        #pragma unroll
        for (int c = 0; c < 3; ++c) {
            int ol = wg * 16 + (l >> 2), kh = l & 3, x = (ol >> 1) & 3;
            const float* p = &Wmw[(c * 64 + ol) * 288 + kh * 8];
            *(bf16x8*)&sWb[(g * 3 + c) * 2048 + ol * 32 + ((kh ^ x) << 3)] = cvt8(p);
        }
    }
    __syncthreads();   // staging + quarters 0-2 visible (barrier drains vmcnt)

    // ---------------- phase A (per group): V_h = Wh@V MFMA; s_h -> sX ----------
    {
        bf16x8 bh = cvt8(&Wh[(oh * 16 + fr) * 32 + fq * 8]);   // L1-hot
        f32x4 va0 = {0,0,0,0}, va1 = {0,0,0,0}, va2 = {0,0,0,0};
        bf16x8 a0 = *(const bf16x8*)&sVT[(g * 96 + 0 * 32 + half * 16 + fr) * VTS + fq * 8];
        bf16x8 a1 = *(const bf16x8*)&sVT[(g * 96 + 1 * 32 + half * 16 + fr) * VTS + fq * 8];
        bf16x8 a2 = *(const bf16x8*)&sVT[(g * 96 + 2 * 32 + half * 16 + fr) * VTS + fq * 8];
        va0 = __builtin_amdgcn_mfma_f32_16x16x32_bf16(a0, bh, va0, 0, 0, 0);
        va1 = __builtin_amdgcn_mfma_f32_16x16x32_bf16(a1, bh, va1, 0, 0, 0);
        va2 = __builtin_amdgcn_mfma_f32_16x16x32_bf16(a2, bh, va2, 0, 0, 0);
        __syncthreads();            // V^T reads done -> sVT writable as V_h^T
        #pragma unroll
        for (int r = 0; r < 4; ++r) {
            int nl = half * 16 + fq * 4 + r;
            int h  = oh * 16 + fr;
            sVT[(g * 96 + 0 * 32 + nl) * VTS + h] = f2b(va0[r]);
            sVT[(g * 96 + 1 * 32 + nl) * VTS + h] = f2b(va1[r]);
            sVT[(g * 96 + 2 * 32 + nl) * VTS + h] = f2b(va2[r]);
            float nrm = sqrtf(fmaf(va0[r], va0[r], fmaf(va1[r], va1[r], va2[r] * va2[r])));
            sX[(g * 32 + nl) * SXS + 256 + h] = f2b(fmaxf(nrm, 1e-4f));
        }
    }
    __syncthreads();                // V_h^T + s_h visible

    // ---------------- main GEMM: 36 quarters, ZERO barriers, counted vmcnt -----
    // acc[mt][q]: col = q*64 + wg*16 + fr; rows = group nodes (2 M-tiles).
    f32x4 acc[2][4];
    #pragma unroll
    for (int mt = 0; mt < 2; ++mt)
        #pragma unroll
        for (int j = 0; j < 4; ++j) acc[mt][j] = (f32x4){0.f, 0.f, 0.f, 0.f};

    const int ol0 = wg * 16 + fr;
    const int bo0 = ol0 * 32 + ((fq ^ ((ol0 >> 1) & 3)) << 3);

    #pragma unroll
    for (int ks = 0; ks < 9; ++ks) {
        bf16x8 a0 = *(const bf16x8*)&sX[(g * 32 + fr) * SXS + ks * 32 + fq * 8];
        bf16x8 a1 = *(const bf16x8*)&sX[(g * 32 + 16 + fr) * SXS + ks * 32 + fq * 8];
        #pragma unroll
        for (int q = 0; q < 4; ++q) {
            const int qi = ks * 4 + q;          // 0..35, static
            if (qi >= 3) {                      // quarter qi landed (per-wave FIFO)
                if (qi <= 33)      asm volatile("s_waitcnt vmcnt(2)" ::: "memory");
                else if (qi == 34) asm volatile("s_waitcnt vmcnt(1)" ::: "memory");
                else               asm volatile("s_waitcnt vmcnt(0)" ::: "memory");
                __builtin_amdgcn_sched_barrier(0);
            }
            const unsigned short* bw = &sWb[(g * 3 + qi % 3) * 2048];
            bf16x8 b0 = *(const bf16x8*)&bw[bo0];
            if (qi <= 32) {                     // refill slot with quarter qi+3
                asm volatile("s_waitcnt lgkmcnt(0)" ::: "memory");  // reads retired
                __builtin_amdgcn_sched_barrier(0);
                if (USE_WS) {
                    glds16(wpack + (qi + 3) * 2048 + wg * 512 + l * 8,
                           &sWb[(g * 3 + qi % 3) * 2048 + wg * 512]);
                } else {
                    int qc = qi + 3, ks2 = qc >> 2, q2 = qc & 3;
                    int ol = wg * 16 + (l >> 2), kh = l & 3, x = (ol >> 1) & 3;
                    const float* p = &Wmw[(q2 * 64 + ol) * 288 + ks2 * 32 + kh * 8];
                    *(bf16x8*)&sWb[(g * 3 + qi % 3) * 2048 + ol * 32 + ((kh ^ x) << 3)] = cvt8(p);
                }
            }
            acc[0][q] = __builtin_amdgcn_mfma_f32_16x16x32_bf16(a0, b0, acc[0][q], 0, 0, 0);
            acc[1][q] = __builtin_amdgcn_mfma_f32_16x16x32_bf16(a1, b0, acc[1][q], 0, 0, 0);
        }
    }
    __syncthreads();            // all A-frag reads done -> sX writable

    // ---------------- epilogue: sigmoid -> sX; relu -> out DIRECT --------------
    float bias[4];
    #pragma unroll
    for (int q = 0; q < 4; ++q) bias[q] = Wmb[q * 64 + wg * 16 + fr];

    #pragma unroll
    for (int mt = 0; mt < 2; ++mt)
        #pragma unroll
        for (int r = 0; r < 4; ++r) {
            int gn = g * 32 + mt * 16 + fq * 4 + r;
            #pragma unroll
            for (int q = 0; q < 4; ++q) {
                int col = q * 64 + wg * 16 + fr;
                float m = acc[mt][q][r] + bias[q];
                sX[gn * SXS + col] = f2b(1.f / (1.f + __expf(-m)));
                out[(size_t)(n0 + gn) * 256 + col] = fmaxf(m, 0.f);
            }
        }
    __syncthreads();

    // ---------------- gate GEMM -> gate in REGISTERS ---------------------------
    float gate[4];
    {
        f32x4 ga = (f32x4){0.f, 0.f, 0.f, 0.f};
        #pragma unroll
        for (int ks = 0; ks < 8; ++ks) {
            bf16x8 a = *(const bf16x8*)&sX[(g * 32 + half * 16 + fr) * SXS + ks * 32 + fq * 8];
            bf16x8 b;
            if (USE_WS) b = *(const bf16x8*)&wpack[73728 + ks * 1024 + (oh * 16 + fr) * 32 + fq * 8];
            else        b = cvt8(&Wgw[(oh * 16 + fr) * 256 + ks * 32 + fq * 8]);
            ga = __builtin_amdgcn_mfma_f32_16x16x32_bf16(a, b, ga, 0, 0, 0);
        }
        float gb = Wgb[oh * 16 + fr];
        #pragma unroll
        for (int r = 0; r < 4; ++r)
            gate[r] = 1.f / (1.f + __expf(-(ga[r] + gb)));
    }
    __syncthreads();            // gate reads of sX done -> sX dead, reusable

    // ---------------- phase D (per group): V_mu MFMA; gate (regs); store -------
    float* sc = (float*)sX;     // [64][96] f32 = 24,576 B <= 37,888 B
    {
        bf16x8 bm = cvt8(&Wmu[(oh * 16 + fr) * 32 + fq * 8]);
        f32x4 m0 = {0,0,0,0}, m1 = {0,0,0,0}, m2 = {0,0,0,0};
        bf16x8 a0 = *(const bf16x8*)&sVT[(g * 96 + 0 * 32 + half * 16 + fr) * VTS + fq * 8];
        bf16x8 a1 = *(const bf16x8*)&sVT[(g * 96 + 1 * 32 + half * 16 + fr) * VTS + fq * 8];
        bf16x8 a2 = *(const bf16x8*)&sVT[(g * 96 + 2 * 32 + half * 16 + fr) * VTS + fq * 8];
        m0 = __builtin_amdgcn_mfma_f32_16x16x32_bf16(a0, bm, m0, 0, 0, 0);
        m1 = __builtin_amdgcn_mfma_f32_16x16x32_bf16(a1, bm, m1, 0, 0, 0);
        m2 = __builtin_amdgcn_mfma_f32_16x16x32_bf16(a2, bm, m2, 0, 0, 0);
        #pragma unroll
        for (int r = 0; r < 4; ++r) {
            int gn = g * 32 + half * 16 + fq * 4 + r;
            int m  = oh * 16 + fr;
            sc[gn * 96 + m * 3 + 0] = gate[r] * m0[r];
            sc[gn * 96 + m * 3 + 1] = gate[r] * m1[r];
            sc[gn * 96 + m * 3 + 2] = gate[r] * m2[r];
        }
    }
    __syncthreads();
    const size_t VBASE = (size_t)NTOT * 256;
    #pragma unroll
    for (int i = 0; i < 3; ++i) {
        int f = i * NT + t;                   // 1536 f4 slots = 64 x 96 floats
        *(float4*)&out[VBASE + (size_t)n0 * 96 + f * 4] = *(const float4*)&((float*)sX)[f * 4];
    }
}

extern "C" void kernel_launch(void* const* d_in, const int* in_sizes, int n_in,
                              void* d_out, int out_size, void* d_ws, size_t ws_size,
                              hipStream_t stream) {
    const float* s   = (const float*)d_in[0];
    const float* V   = (const float*)d_in[1];
    const float* Wh  = (const float*)d_in[2];
    const float* Wmu = (const float*)d_in[3];
    const float* Wmw = (const float*)d_in[4];
    const float* Wmb = (const float*)d_in[5];
    const float* Wgw = (const float*)d_in[6];
    const float* Wgb = (const float*)d_in[7];
    float* out = (float*)d_out;

    dim3 grid(NTOT / BN);   // 4096
    dim3 block(NT);         // 512

    if (ws_size >= 163840) {
        pack_w<<<320, 256, 0, stream>>>(Wmw, Wgw, (unsigned short*)d_ws);
        gvp_main<1><<<grid, block, 0, stream>>>(s, V, Wh, Wmu, Wmw, Wmb, Wgw, Wgb,
                                                (const unsigned short*)d_ws, out);
    } else {
        gvp_main<0><<<grid, block, 0, stream>>>(s, V, Wh, Wmu, Wmw, Wmb, Wgw, Wgb,
                                                nullptr, out);
    }
}

// Round 17
// 209.118 us; speedup vs baseline: 1.0478x; 1.0478x over previous
//
#include <hip/hip_runtime.h>

#define NTOT 262144
#define BN   32
#define NT   256
#define SXS  296     // sX row stride in shorts (288 + 8 pad; conflict-free b128 reads)
#define VTS  36      // V^T / V_h^T row stride in shorts (32 + 4 pad)

typedef __attribute__((ext_vector_type(8))) short bf16x8;
typedef __attribute__((ext_vector_type(4))) float f32x4;

static __device__ __forceinline__ unsigned short f2b(float x) {
    union { float f; unsigned u; } c; c.f = x;
    unsigned r = c.u + 0x7FFFu + ((c.u >> 16) & 1u);   // RNE
    return (unsigned short)(r >> 16);
}
static __device__ __forceinline__ float b2f(unsigned short h) {
    union { unsigned u; float f; } c; c.u = ((unsigned)h) << 16; return c.f;
}
static __device__ __forceinline__ bf16x8 cvt8(const float* p) {
    float4 x = *(const float4*)p, y = *(const float4*)(p + 4);
    bf16x8 r;
    r[0] = (short)f2b(x.x); r[1] = (short)f2b(x.y); r[2] = (short)f2b(x.z); r[3] = (short)f2b(x.w);
    r[4] = (short)f2b(y.x); r[5] = (short)f2b(y.y); r[6] = (short)f2b(y.z); r[7] = (short)f2b(y.w);
    return r;
}
static __device__ __forceinline__ void glds16(const unsigned short* g, void* l) {
    __builtin_amdgcn_global_load_lds(
        (const __attribute__((address_space(1))) void*)g,
        (__attribute__((address_space(3))) void*)l, 16, 0, 0);
}

// Pack W_m_w -> bf16, 18 half-chunks [128 cols][32 k] (it = ks*2 + ch),
// XOR-swizzled on k (kk ^= ((ol>>1)&3)<<3) -> conflict-free B-frag b128 reads.
// W_g_w -> bf16 k-chunked at offset 73728.
__global__ void pack_w(const float* __restrict__ Wmw, const float* __restrict__ Wgw,
                       unsigned short* __restrict__ wp) {
    int t = blockIdx.x * 256 + threadIdx.x;
    if (t < 73728) {
        int o = t / 288, k = t % 288;
        int ks = k >> 5, kk = k & 31, ch = o >> 7, ol = o & 127;
        int kks = kk ^ (((ol >> 1) & 3) << 3);
        wp[(ks * 2 + ch) * 4096 + ol * 32 + kks] = f2b(Wmw[t]);
    } else if (t < 81920) {
        int j = t - 73728;
        int o = j >> 8, k = j & 255;
        wp[73728 + (k >> 5) * 1024 + o * 32 + (k & 31)] = f2b(Wgw[j]);
    }
}

// K-loop is BARRIER-FREE: each wave stages and reads ONLY its own 2 KB W slice
// (cols [32w,32w+32)), so no cross-wave hazard exists. Counted vmcnt(2) keeps
// the next chunk's glds in flight (never drained mid-loop); lgkmcnt(0)+
// sched_barrier guards each dbuf-slot overwrite (same-wave RAW).
template<int USE_WS>
__global__ __launch_bounds__(NT, 3)
void gvp_main(const float* __restrict__ s, const float* __restrict__ V,
              const float* __restrict__ Wh, const float* __restrict__ Wmu,
              const float* __restrict__ Wmw, const float* __restrict__ Wmb,
              const float* __restrict__ Wgw, const float* __restrict__ Wgb,
              const unsigned short* __restrict__ wpack,
              float* __restrict__ out)
{
    // sX  bf16 [32][296] 18944 B: s | s_h -> sigmoid(s_m) | gate
    // sWb 2 x 4096 shorts 16384 B: W half-chunk dbuf -> relu f32 [16][256] -> V_dash f32
    // sVT bf16 [96][36]   6912 B: V^T (c-major), then V_h^T    (total 42,240 B)
    __shared__ __attribute__((aligned(16))) unsigned short sX[BN * SXS];
    __shared__ __attribute__((aligned(16))) unsigned short sWb[2 * 4096];
    __shared__ __attribute__((aligned(16))) unsigned short sVT[96 * VTS];

    const int t  = threadIdx.x;
    const int w  = t >> 6, l = t & 63;
    const int fr = l & 15, fq = l >> 4;
    const int n0 = blockIdx.x * BN;
    const int half = w & 1, oh = w >> 1;   // phase A/D wave mapping

    // ---------------- prologue: issue W half-chunks 0,1 (async) ----------------
    if (USE_WS) {
        #pragma unroll
        for (int c = 0; c < 2; ++c) {
            const unsigned short* src = wpack + c * 4096 + w * 1024 + l * 8;
            unsigned short* dst = sWb + c * 4096 + w * 1024;
            glds16(src, dst);
            glds16(src + 512, dst + 512);
        }
    }

    // ---------------- stage s -> sX (bf16), V -> sVT (c-major transpose) -------
    #pragma unroll
    for (int i = 0; i < 8; ++i) {
        int n = i * 4 + w;
        float4 x4 = *(const float4*)&s[(size_t)(n0 + n) * 256 + 4 * l];
        ushort4 h4; h4.x = f2b(x4.x); h4.y = f2b(x4.y); h4.z = f2b(x4.z); h4.w = f2b(x4.w);
        *(ushort4*)&sX[n * SXS + 4 * l] = h4;
    }
    {   // thread t -> node n = t>>3, v-quad vq = t&7: 48 consecutive bytes in,
        // three short4 LDS writes out (no div/mod, vectorized)
        int n = t >> 3, vq = t & 7;
        const float* p = &V[(size_t)(n0 + n) * 96 + vq * 12];
        float4 q0 = *(const float4*)(p);
        float4 q1 = *(const float4*)(p + 4);
        float4 q2 = *(const float4*)(p + 8);
        ushort4 c0 = { f2b(q0.x), f2b(q0.w), f2b(q1.z), f2b(q2.y) };   // c=0, dv=0..3
        ushort4 c1 = { f2b(q0.y), f2b(q1.x), f2b(q1.w), f2b(q2.z) };   // c=1
        ushort4 c2 = { f2b(q0.z), f2b(q1.y), f2b(q2.x), f2b(q2.w) };   // c=2
        *(ushort4*)&sVT[(0 * 32 + n) * VTS + vq * 4] = c0;
        *(ushort4*)&sVT[(1 * 32 + n) * VTS + vq * 4] = c1;
        *(ushort4*)&sVT[(2 * 32 + n) * VTS + vq * 4] = c2;
    }
    if (!USE_WS) {   // fallback: cvt-stage half-chunks 0,1
        #pragma unroll
        for (int c = 0; c < 2; ++c) {
            int ol = w * 32 + (l >> 1), kh = l & 1, x = (ol >> 1) & 3;
            const float* p = &Wmw[(c * 128 + ol) * 288 + kh * 16];
            unsigned short* dst = sWb + c * 4096;
            *(bf16x8*)&dst[ol * 32 + (((kh * 2 + 0) ^ x) << 3)] = cvt8(p);
            *(bf16x8*)&dst[ol * 32 + (((kh * 2 + 1) ^ x) << 3)] = cvt8(p + 8);
        }
    }
    __syncthreads();   // staging + chunks 0,1 visible (this barrier drains vmcnt)

    // ---------------- phase A: V_h = Wh@V via MFMA; s_h -> sX[.,256..] ---------
    {
        bf16x8 bh = cvt8(&Wh[(oh * 16 + fr) * 32 + fq * 8]);   // L1-hot
        f32x4 va0 = {0,0,0,0}, va1 = {0,0,0,0}, va2 = {0,0,0,0};
        bf16x8 a0 = *(const bf16x8*)&sVT[(0 * 32 + half * 16 + fr) * VTS + fq * 8];
        bf16x8 a1 = *(const bf16x8*)&sVT[(1 * 32 + half * 16 + fr) * VTS + fq * 8];
        bf16x8 a2 = *(const bf16x8*)&sVT[(2 * 32 + half * 16 + fr) * VTS + fq * 8];
        va0 = __builtin_amdgcn_mfma_f32_16x16x32_bf16(a0, bh, va0, 0, 0, 0);
        va1 = __builtin_amdgcn_mfma_f32_16x16x32_bf16(a1, bh, va1, 0, 0, 0);
        va2 = __builtin_amdgcn_mfma_f32_16x16x32_bf16(a2, bh, va2, 0, 0, 0);
        __syncthreads();            // V^T reads done -> sVT writable as V_h^T
        #pragma unroll
        for (int r = 0; r < 4; ++r) {
            int nl = half * 16 + fq * 4 + r;
            int h  = oh * 16 + fr;
            sVT[(0 * 32 + nl) * VTS + h] = f2b(va0[r]);
            sVT[(1 * 32 + nl) * VTS + h] = f2b(va1[r]);
            sVT[(2 * 32 + nl) * VTS + h] = f2b(va2[r]);
            float nrm = sqrtf(fmaf(va0[r], va0[r], fmaf(va1[r], va1[r], va2[r] * va2[r])));
            sX[nl * SXS + 256 + h] = f2b(fmaxf(nrm, 1e-4f));
        }
    }
    __syncthreads();                // V_h^T + s_h visible

    // ---------------- main GEMM: 18 iters, ZERO barriers, counted vmcnt --------
    f32x4 acc[2][4];
    #pragma unroll
    for (int mt = 0; mt < 2; ++mt)
        #pragma unroll
        for (int j = 0; j < 4; ++j) acc[mt][j] = (f32x4){0.f, 0.f, 0.f, 0.f};

    const int ol0 = w * 32 + fr, ol1 = ol0 + 16;
    const int bo0 = ol0 * 32 + ((fq ^ ((ol0 >> 1) & 3)) << 3);
    const int bo1 = ol1 * 32 + ((fq ^ ((ol1 >> 1) & 3)) << 3);

    #pragma unroll
    for (int it = 0; it < 18; ++it) {
        if (it >= 2) {          // chunk it's glds landed (per-wave FIFO count)
            if (it <= 16) asm volatile("s_waitcnt vmcnt(2)" ::: "memory");
            else          asm volatile("s_waitcnt vmcnt(0)" ::: "memory");
            __builtin_amdgcn_sched_barrier(0);
        }
        const int ks = it >> 1;
        const unsigned short* bw = sWb + (it & 1) * 4096;
        bf16x8 a0 = *(const bf16x8*)&sX[fr * SXS + ks * 32 + fq * 8];
        bf16x8 a1 = *(const bf16x8*)&sX[(16 + fr) * SXS + ks * 32 + fq * 8];
        bf16x8 b0 = *(const bf16x8*)&bw[bo0];
        bf16x8 b1 = *(const bf16x8*)&bw[bo1];
        if (it < 16) {          // refill this slot with chunk it+2 (wave-private)
            asm volatile("s_waitcnt lgkmcnt(0)" ::: "memory");   // slot reads retired
            __builtin_amdgcn_sched_barrier(0);
            if (USE_WS) {
                const unsigned short* src = wpack + (it + 2) * 4096 + w * 1024 + l * 8;
                unsigned short* dst = sWb + (it & 1) * 4096 + w * 1024;
                glds16(src, dst);
                glds16(src + 512, dst + 512);
            } else {
                int it2 = it + 2, ks2 = it2 >> 1, ch2 = it2 & 1;
                int ol = w * 32 + (l >> 1), kh = l & 1, x = (ol >> 1) & 3;
                const float* p = &Wmw[(ch2 * 128 + ol) * 288 + ks2 * 32 + kh * 16];
                unsigned short* dst = sWb + (it & 1) * 4096;
                *(bf16x8*)&dst[ol * 32 + (((kh * 2 + 0) ^ x) << 3)] = cvt8(p);
                *(bf16x8*)&dst[ol * 32 + (((kh * 2 + 1) ^ x) << 3)] = cvt8(p + 8);
            }
        }
        const int ji = (it & 1) * 2;   // static under full unroll
        acc[0][ji + 0] = __builtin_amdgcn_mfma_f32_16x16x32_bf16(a0, b0, acc[0][ji + 0], 0, 0, 0);
        acc[1][ji + 0] = __builtin_amdgcn_mfma_f32_16x16x32_bf16(a1, b0, acc[1][ji + 0], 0, 0, 0);
        acc[0][ji + 1] = __builtin_amdgcn_mfma_f32_16x16x32_bf16(a0, b1, acc[0][ji + 1], 0, 0, 0);
        acc[1][ji + 1] = __builtin_amdgcn_mfma_f32_16x16x32_bf16(a1, b1, acc[1][ji + 1], 0, 0, 0);
    }
    __syncthreads();            // all A-frag reads done -> sX writable

    // ---------------- epilogue: sigmoid -> sX; relu restaged via sWb (skewed) --
    float bias[4];
    #pragma unroll
    for (int ji = 0; ji < 4; ++ji)
        bias[ji] = Wmb[(ji >> 1) * 128 + w * 32 + (ji & 1) * 16 + fr];

    // bank skew: col ^ sk, sk = {0,16,8,24}[fq] -> fq groups split across bank
    // halves (2-way instead of 4-way). Bijective, float4-aligned, read-back aware.
    const int skw = ((fq & 1) << 4) | ((fq >> 1) << 3);
    float* sRel = (float*)sWb;  // [16][256] f32 per pass (16384 B = sWb exactly)
    #pragma unroll
    for (int mt = 0; mt < 2; ++mt) {
        #pragma unroll
        for (int r = 0; r < 4; ++r) {
            int row  = fq * 4 + r;
            int node = mt * 16 + row;
            #pragma unroll
            for (int ji = 0; ji < 4; ++ji) {
                int col = (ji >> 1) * 128 + w * 32 + (ji & 1) * 16 + fr;
                float m = acc[mt][ji][r] + bias[ji];
                sX[node * SXS + col] = f2b(1.f / (1.f + __expf(-m)));
                sRel[row * 256 + (col ^ skw)] = fmaxf(m, 0.f);
            }
        }
        __syncthreads();
        #pragma unroll
        for (int i = 0; i < 4; ++i) {
            int flat = i * NT + t;            // 1024 f4 slots = 16 rows x 64
            int row = flat >> 6, c4 = flat & 63;
            int sk2 = (((row >> 2) & 1) << 4) | (((row >> 3) & 1) << 3);
            float4 v4 = *(const float4*)&sRel[row * 256 + ((c4 * 4) ^ sk2)];
            *(float4*)&out[(size_t)(n0 + mt * 16 + row) * 256 + c4 * 4] = v4;
        }
        __syncthreads();
    }

    // ---------------- gate GEMM; gate bf16 -> sX[.,256..] ----------------------
    {
        const int gmt = w & 1, gnt = w >> 1;
        f32x4 g = (f32x4){0.f, 0.f, 0.f, 0.f};
        #pragma unroll
        for (int ks = 0; ks < 8; ++ks) {
            bf16x8 a = *(const bf16x8*)&sX[(gmt * 16 + fr) * SXS + ks * 32 + fq * 8];
            bf16x8 b;
            if (USE_WS) b = *(const bf16x8*)&wpack[73728 + ks * 1024 + (gnt * 16 + fr) * 32 + fq * 8];
            else        b = cvt8(&Wgw[(gnt * 16 + fr) * 256 + ks * 32 + fq * 8]);
            g = __builtin_amdgcn_mfma_f32_16x16x32_bf16(a, b, g, 0, 0, 0);
        }
        int mo = gnt * 16 + fr;
        float gb = Wgb[mo];
        #pragma unroll
        for (int r = 0; r < 4; ++r) {
            int node = gmt * 16 + fq * 4 + r;
            sX[node * SXS + 256 + mo] = f2b(1.f / (1.f + __expf(-(g[r] + gb))));
        }
    }
    __syncthreads();            // gate visible; sWb dead -> f32 V_dash scratch

    // ---------------- phase D: V_mu = Wmu@V_h via MFMA; gate; store ------------
    float* sc = (float*)sWb;    // [32][96] f32 = 12288 B <= 16384 B
    {
        bf16x8 bm = cvt8(&Wmu[(oh * 16 + fr) * 32 + fq * 8]);
        f32x4 m0 = {0,0,0,0}, m1 = {0,0,0,0}, m2 = {0,0,0,0};
        bf16x8 a0 = *(const bf16x8*)&sVT[(0 * 32 + half * 16 + fr) * VTS + fq * 8];
        bf16x8 a1 = *(const bf16x8*)&sVT[(1 * 32 + half * 16 + fr) * VTS + fq * 8];
        bf16x8 a2 = *(const bf16x8*)&sVT[(2 * 32 + half * 16 + fr) * VTS + fq * 8];
        m0 = __builtin_amdgcn_mfma_f32_16x16x32_bf16(a0, bm, m0, 0, 0, 0);
        m1 = __builtin_amdgcn_mfma_f32_16x16x32_bf16(a1, bm, m1, 0, 0, 0);
        m2 = __builtin_amdgcn_mfma_f32_16x16x32_bf16(a2, bm, m2, 0, 0, 0);
        #pragma unroll
        for (int r = 0; r < 4; ++r) {
            int node = half * 16 + fq * 4 + r;
            int m    = oh * 16 + fr;
            float g  = b2f(sX[node * SXS + 256 + m]);
            sc[node * 96 + m * 3 + 0] = g * m0[r];
            sc[node * 96 + m * 3 + 1] = g * m1[r];
            sc[node * 96 + m * 3 + 2] = g * m2[r];
        }
    }
    __syncthreads();
    const size_t VBASE = (size_t)NTOT * 256;
    #pragma unroll
    for (int i = 0; i < 3; ++i) {
        int f = i * NT + t;
        *(float4*)&out[VBASE + (size_t)n0 * 96 + f * 4] = *(const float4*)&sc[f * 4];
    }
}

extern "C" void kernel_launch(void* const* d_in, const int* in_sizes, int n_in,
                              void* d_out, int out_size, void* d_ws, size_t ws_size,
                              hipStream_t stream) {
    const float* s   = (const float*)d_in[0];
    const float* V   = (const float*)d_in[1];
    const float* Wh  = (const float*)d_in[2];
    const float* Wmu = (const float*)d_in[3];
    const float* Wmw = (const float*)d_in[4];
    const float* Wmb = (const float*)d_in[5];
    const float* Wgw = (const float*)d_in[6];
    const float* Wgb = (const float*)d_in[7];
    float* out = (float*)d_out;

    dim3 grid(NTOT / BN);   // 8192
    dim3 block(NT);         // 256

    if (ws_size >= 163840) {
        pack_w<<<320, 256, 0, stream>>>(Wmw, Wgw, (unsigned short*)d_ws);
        gvp_main<1><<<grid, block, 0, stream>>>(s, V, Wh, Wmu, Wmw, Wmb, Wgw, Wgb,
                                                (const unsigned short*)d_ws, out);
    } else {
        gvp_main<0><<<grid, block, 0, stream>>>(s, V, Wh, Wmu, Wmw, Wmb, Wgw, Wgb,
                                                nullptr, out);
    }
}

// Round 19
// 208.722 us; speedup vs baseline: 1.0498x; 1.0019x over previous
//
#include <hip/hip_runtime.h>

#define NTOT 262144
#define BN   32
#define NT   256
#define SXS  296     // sX row stride in shorts (288 + 8 pad; conflict-free b128 reads)
#define VTS  36      // V^T / V_h^T row stride in shorts (32 + 4 pad)

typedef __attribute__((ext_vector_type(8))) short bf16x8;
typedef __attribute__((ext_vector_type(4))) float f32x4;

// pk2 (v_cvt_pk_bf16_f32) is used ONLY for LOAD-SOURCED data. r18's A/B test
// showed pk2 corrupts output 1 when the asm reads MFMA-destination registers
// directly (phase-A write-back): hipcc's MFMA->inline-asm hazard handling is
// unreliable (cf. guide rule #18). All MFMA-downstream conversions use f2b
// (plain C -> compiler inserts the required wait states).
static __device__ __forceinline__ unsigned pk2(float lo, float hi) {
    unsigned r;
    asm("v_cvt_pk_bf16_f32 %0, %1, %2" : "=v"(r) : "v"(lo), "v"(hi));
    return r;
}
static __device__ __forceinline__ unsigned short f2b(float x) {
    union { float f; unsigned u; } c; c.f = x;
    unsigned r = c.u + 0x7FFFu + ((c.u >> 16) & 1u);   // RNE
    return (unsigned short)(r >> 16);
}
static __device__ __forceinline__ float b2f(unsigned short h) {
    union { unsigned u; float f; } c; c.u = ((unsigned)h) << 16; return c.f;
}
static __device__ __forceinline__ bf16x8 cvt8(const float* p) {   // load-sourced only
    float4 x = *(const float4*)p, y = *(const float4*)(p + 4);
    union { unsigned u[4]; bf16x8 v; } r;
    r.u[0] = pk2(x.x, x.y); r.u[1] = pk2(x.z, x.w);
    r.u[2] = pk2(y.x, y.y); r.u[3] = pk2(y.z, y.w);
    return r.v;
}
static __device__ __forceinline__ void glds16(const unsigned short* g, void* l) {
    __builtin_amdgcn_global_load_lds(
        (const __attribute__((address_space(1))) void*)g,
        (__attribute__((address_space(3))) void*)l, 16, 0, 0);
}

// Pack W_m_w -> bf16, 18 half-chunks [128 cols][32 k] (it = ks*2 + ch),
// XOR-swizzled on k (kk ^= ((ol>>1)&3)<<3) -> conflict-free B-frag b128 reads.
// W_g_w -> bf16 k-chunked at offset 73728. (Load->convert->store only: pk2 safe.)
__global__ void pack_w(const float* __restrict__ Wmw, const float* __restrict__ Wgw,
                       unsigned short* __restrict__ wp) {
    int t = blockIdx.x * 256 + threadIdx.x;
    if (t < 73728) {
        int o = t / 288, k = t % 288;
        int ks = k >> 5, kk = k & 31, ch = o >> 7, ol = o & 127;
        int kks = kk ^ (((ol >> 1) & 3) << 3);
        wp[(ks * 2 + ch) * 4096 + ol * 32 + kks] = (unsigned short)pk2(Wmw[t], Wmw[t]);
    } else if (t < 81920) {
        int j = t - 73728;
        int o = j >> 8, k = j & 255;
        wp[73728 + (k >> 5) * 1024 + o * 32 + (k & 31)] = (unsigned short)pk2(Wgw[j], Wgw[j]);
    }
}

// K-loop is BARRIER-FREE: each wave stages and reads ONLY its own 2 KB W slice
// (cols [32w,32w+32)), so no cross-wave hazard exists. Counted vmcnt(2) keeps
// the next chunk's glds in flight (never drained mid-loop); lgkmcnt(0)+
// sched_barrier guards each dbuf-slot overwrite (same-wave RAW).
template<int USE_WS>
__global__ __launch_bounds__(NT, 3)
void gvp_main(const float* __restrict__ s, const float* __restrict__ V,
              const float* __restrict__ Wh, const float* __restrict__ Wmu,
              const float* __restrict__ Wmw, const float* __restrict__ Wmb,
              const float* __restrict__ Wgw, const float* __restrict__ Wgb,
              const unsigned short* __restrict__ wpack,
              float* __restrict__ out)
{
    // sX  bf16 [32][296] 18944 B: s | s_h -> sigmoid(s_m) | gate
    // sWb 2 x 4096 shorts 16384 B: W half-chunk dbuf -> relu f32 [16][256] -> V_dash f32
    // sVT bf16 [96][36]   6912 B: V^T (c-major), then V_h^T    (total 42,240 B)
    __shared__ __attribute__((aligned(16))) unsigned short sX[BN * SXS];
    __shared__ __attribute__((aligned(16))) unsigned short sWb[2 * 4096];
    __shared__ __attribute__((aligned(16))) unsigned short sVT[96 * VTS];

    const int t  = threadIdx.x;
    const int w  = t >> 6, l = t & 63;
    const int fr = l & 15, fq = l >> 4;
    const int n0 = blockIdx.x * BN;
    const int half = w & 1, oh = w >> 1;   // phase A/D wave mapping

    // ---------------- prologue: issue W half-chunks 0,1 (async) ----------------
    if (USE_WS) {
        #pragma unroll
        for (int c = 0; c < 2; ++c) {
            const unsigned short* src = wpack + c * 4096 + w * 1024 + l * 8;
            unsigned short* dst = sWb + c * 4096 + w * 1024;
            glds16(src, dst);
            glds16(src + 512, dst + 512);
        }
    }

    // ---------------- stage s -> sX (pk2: load-sourced), V -> sVT --------------
    #pragma unroll
    for (int i = 0; i < 8; ++i) {
        int n = i * 4 + w;
        float4 x4 = *(const float4*)&s[(size_t)(n0 + n) * 256 + 4 * l];
        uint2 h2 = { pk2(x4.x, x4.y), pk2(x4.z, x4.w) };
        *(uint2*)&sX[n * SXS + 4 * l] = h2;
    }
    {   // thread t -> node n = t>>3, v-quad vq = t&7 (no div/mod, 8B writes)
        int n = t >> 3, vq = t & 7;
        const float* p = &V[(size_t)(n0 + n) * 96 + vq * 12];
        float4 q0 = *(const float4*)(p);
        float4 q1 = *(const float4*)(p + 4);
        float4 q2 = *(const float4*)(p + 8);
        uint2 c0 = { pk2(q0.x, q0.w), pk2(q1.z, q2.y) };   // c=0, dv=0..3
        uint2 c1 = { pk2(q0.y, q1.x), pk2(q1.w, q2.z) };   // c=1
        uint2 c2 = { pk2(q0.z, q1.y), pk2(q2.x, q2.w) };   // c=2
        *(uint2*)&sVT[(0 * 32 + n) * VTS + vq * 4] = c0;
        *(uint2*)&sVT[(1 * 32 + n) * VTS + vq * 4] = c1;
        *(uint2*)&sVT[(2 * 32 + n) * VTS + vq * 4] = c2;
    }
    if (!USE_WS) {   // fallback: cvt-stage half-chunks 0,1 (load-sourced)
        #pragma unroll
        for (int c = 0; c < 2; ++c) {
            int ol = w * 32 + (l >> 1), kh = l & 1, x = (ol >> 1) & 3;
            const float* p = &Wmw[(c * 128 + ol) * 288 + kh * 16];
            unsigned short* dst = sWb + c * 4096;
            *(bf16x8*)&dst[ol * 32 + (((kh * 2 + 0) ^ x) << 3)] = cvt8(p);
            *(bf16x8*)&dst[ol * 32 + (((kh * 2 + 1) ^ x) << 3)] = cvt8(p + 8);
        }
    }
    __syncthreads();   // staging + chunks 0,1 visible (this barrier drains vmcnt)

    // ---------------- phase A: V_h = Wh@V via MFMA; s_h -> sX[.,256..] ---------
    // Write-back uses f2b (plain C): va* are MFMA destinations; inline-asm pk2
    // reading them directly was the r15/16/18 output-1 corruption site.
    {
        bf16x8 bh = cvt8(&Wh[(oh * 16 + fr) * 32 + fq * 8]);   // L1-hot, load-sourced
        f32x4 va0 = {0,0,0,0}, va1 = {0,0,0,0}, va2 = {0,0,0,0};
        bf16x8 a0 = *(const bf16x8*)&sVT[(0 * 32 + half * 16 + fr) * VTS + fq * 8];
        bf16x8 a1 = *(const bf16x8*)&sVT[(1 * 32 + half * 16 + fr) * VTS + fq * 8];
        bf16x8 a2 = *(const bf16x8*)&sVT[(2 * 32 + half * 16 + fr) * VTS + fq * 8];
        va0 = __builtin_amdgcn_mfma_f32_16x16x32_bf16(a0, bh, va0, 0, 0, 0);
        va1 = __builtin_amdgcn_mfma_f32_16x16x32_bf16(a1, bh, va1, 0, 0, 0);
        va2 = __builtin_amdgcn_mfma_f32_16x16x32_bf16(a2, bh, va2, 0, 0, 0);
        __syncthreads();            // V^T reads done -> sVT writable as V_h^T
        #pragma unroll
        for (int r = 0; r < 4; ++r) {
            int nl = half * 16 + fq * 4 + r;
            int h  = oh * 16 + fr;
            sVT[(0 * 32 + nl) * VTS + h] = f2b(va0[r]);
            sVT[(1 * 32 + nl) * VTS + h] = f2b(va1[r]);
            sVT[(2 * 32 + nl) * VTS + h] = f2b(va2[r]);
            float nrm = sqrtf(fmaf(va0[r], va0[r], fmaf(va1[r], va1[r], va2[r] * va2[r])));
            sX[nl * SXS + 256 + h] = f2b(fmaxf(nrm, 1e-4f));
        }
    }
    __syncthreads();                // V_h^T + s_h visible

    // ---------------- main GEMM: 18 iters, ZERO barriers, counted vmcnt --------
    f32x4 acc[2][4];
    #pragma unroll
    for (int mt = 0; mt < 2; ++mt)
        #pragma unroll
        for (int j = 0; j < 4; ++j) acc[mt][j] = (f32x4){0.f, 0.f, 0.f, 0.f};

    const int ol0 = w * 32 + fr, ol1 = ol0 + 16;
    const int bo0 = ol0 * 32 + ((fq ^ ((ol0 >> 1) & 3)) << 3);
    const int bo1 = ol1 * 32 + ((fq ^ ((ol1 >> 1) & 3)) << 3);

    #pragma unroll
    for (int it = 0; it < 18; ++it) {
        if (it >= 2) {          // chunk it's glds landed (per-wave FIFO count)
            if (it <= 16) asm volatile("s_waitcnt vmcnt(2)" ::: "memory");
            else          asm volatile("s_waitcnt vmcnt(0)" ::: "memory");
            __builtin_amdgcn_sched_barrier(0);
        }
        const int ks = it >> 1;
        const unsigned short* bw = sWb + (it & 1) * 4096;
        bf16x8 a0 = *(const bf16x8*)&sX[fr * SXS + ks * 32 + fq * 8];
        bf16x8 a1 = *(const bf16x8*)&sX[(16 + fr) * SXS + ks * 32 + fq * 8];
        bf16x8 b0 = *(const bf16x8*)&bw[bo0];
        bf16x8 b1v = *(const bf16x8*)&bw[bo1];
        if (it < 16) {          // refill this slot with chunk it+2 (wave-private)
            asm volatile("s_waitcnt lgkmcnt(0)" ::: "memory");   // slot reads retired
            __builtin_amdgcn_sched_barrier(0);
            if (USE_WS) {
                const unsigned short* src = wpack + (it + 2) * 4096 + w * 1024 + l * 8;
                unsigned short* dst = sWb + (it & 1) * 4096 + w * 1024;
                glds16(src, dst);
                glds16(src + 512, dst + 512);
            } else {
                int it2 = it + 2, ks2 = it2 >> 1, ch2 = it2 & 1;
                int ol = w * 32 + (l >> 1), kh = l & 1, x = (ol >> 1) & 3;
                const float* p = &Wmw[(ch2 * 128 + ol) * 288 + ks2 * 32 + kh * 16];
                unsigned short* dst = sWb + (it & 1) * 4096;
                *(bf16x8*)&dst[ol * 32 + (((kh * 2 + 0) ^ x) << 3)] = cvt8(p);
                *(bf16x8*)&dst[ol * 32 + (((kh * 2 + 1) ^ x) << 3)] = cvt8(p + 8);
            }
        }
        const int ji = (it & 1) * 2;   // static under full unroll
        acc[0][ji + 0] = __builtin_amdgcn_mfma_f32_16x16x32_bf16(a0, b0, acc[0][ji + 0], 0, 0, 0);
        acc[1][ji + 0] = __builtin_amdgcn_mfma_f32_16x16x32_bf16(a1, b0, acc[1][ji + 0], 0, 0, 0);
        acc[0][ji + 1] = __builtin_amdgcn_mfma_f32_16x16x32_bf16(a0, b1v, acc[0][ji + 1], 0, 0, 0);
        acc[1][ji + 1] = __builtin_amdgcn_mfma_f32_16x16x32_bf16(a1, b1v, acc[1][ji + 1], 0, 0, 0);
    }
    __syncthreads();            // all A-frag reads done -> sX writable

    // ---------------- epilogue: sigmoid -> sX (f2b); relu restaged via sWb -----
    float bias[4];
    #pragma unroll
    for (int ji = 0; ji < 4; ++ji)
        bias[ji] = Wmb[(ji >> 1) * 128 + w * 32 + (ji & 1) * 16 + fr];

    // bank skew: col ^ sk, sk = {0,16,8,24}[fq] -> fq groups split across bank
    // halves (2-way instead of 4-way). Bijective, float4-aligned, read-back aware.
    const int skw = ((fq & 1) << 4) | ((fq >> 1) << 3);
    float* sRel = (float*)sWb;  // [16][256] f32 per pass (16384 B = sWb exactly)
    #pragma unroll
    for (int mt = 0; mt < 2; ++mt) {
        #pragma unroll
        for (int r = 0; r < 4; ++r) {
            int row  = fq * 4 + r;
            int node = mt * 16 + row;
            #pragma unroll
            for (int ji = 0; ji < 4; ++ji) {
                int col = (ji >> 1) * 128 + w * 32 + (ji & 1) * 16 + fr;
                float m = acc[mt][ji][r] + bias[ji];
                sX[node * SXS + col] = f2b(1.f / (1.f + __expf(-m)));
                sRel[row * 256 + (col ^ skw)] = fmaxf(m, 0.f);
            }
        }
        __syncthreads();
        #pragma unroll
        for (int i = 0; i < 4; ++i) {
            int flat = i * NT + t;            // 1024 f4 slots = 16 rows x 64
            int row = flat >> 6, c4 = flat & 63;
            int sk2 = (((row >> 2) & 1) << 4) | (((row >> 3) & 1) << 3);
            float4 v4 = *(const float4*)&sRel[row * 256 + ((c4 * 4) ^ sk2)];
            *(float4*)&out[(size_t)(n0 + mt * 16 + row) * 256 + c4 * 4] = v4;
        }
        __syncthreads();
    }

    // ---------------- gate GEMM; gate bf16 (f2b) -> sX[.,256..] ----------------
    {
        const int gmt = w & 1, gnt = w >> 1;
        f32x4 g = (f32x4){0.f, 0.f, 0.f, 0.f};
        #pragma unroll
        for (int ks = 0; ks < 8; ++ks) {
            bf16x8 a = *(const bf16x8*)&sX[(gmt * 16 + fr) * SXS + ks * 32 + fq * 8];
            bf16x8 b;
            if (USE_WS) b = *(const bf16x8*)&wpack[73728 + ks * 1024 + (gnt * 16 + fr) * 32 + fq * 8];
            else        b = cvt8(&Wgw[(gnt * 16 + fr) * 256 + ks * 32 + fq * 8]);
            g = __builtin_amdgcn_mfma_f32_16x16x32_bf16(a, b, g, 0, 0, 0);
        }
        int mo = gnt * 16 + fr;
        float gb = Wgb[mo];
        #pragma unroll
        for (int r = 0; r < 4; ++r) {
            int node = gmt * 16 + fq * 4 + r;
            sX[node * SXS + 256 + mo] = f2b(1.f / (1.f + __expf(-(g[r] + gb))));
        }
    }
    __syncthreads();            // gate visible; sWb dead -> f32 V_dash scratch

    // ---------------- phase D: V_mu = Wmu@V_h via MFMA; gate; store ------------
    float* sc = (float*)sWb;    // [32][96] f32 = 12288 B <= 16384 B
    {
        bf16x8 bm = cvt8(&Wmu[(oh * 16 + fr) * 32 + fq * 8]);   // load-sourced
        f32x4 m0 = {0,0,0,0}, m1 = {0,0,0,0}, m2 = {0,0,0,0};
        bf16x8 a0 = *(const bf16x8*)&sVT[(0 * 32 + half * 16 + fr) * VTS + fq * 8];
        bf16x8 a1 = *(const bf16x8*)&sVT[(1 * 32 + half * 16 + fr) * VTS + fq * 8];
        bf16x8 a2 = *(const bf16x8*)&sVT[(2 * 32 + half * 16 + fr) * VTS + fq * 8];
        m0 = __builtin_amdgcn_mfma_f32_16x16x32_bf16(a0, bm, m0, 0, 0, 0);
        m1 = __builtin_amdgcn_mfma_f32_16x16x32_bf16(a1, bm, m1, 0, 0, 0);
        m2 = __builtin_amdgcn_mfma_f32_16x16x32_bf16(a2, bm, m2, 0, 0, 0);
        #pragma unroll
        for (int r = 0; r < 4; ++r) {
            int node = half * 16 + fq * 4 + r;
            int m    = oh * 16 + fr;
            float g  = b2f(sX[node * SXS + 256 + m]);
            sc[node * 96 + m * 3 + 0] = g * m0[r];
            sc[node * 96 + m * 3 + 1] = g * m1[r];
            sc[node * 96 + m * 3 + 2] = g * m2[r];
        }
    }
    __syncthreads();
    const size_t VBASE = (size_t)NTOT * 256;
    #pragma unroll
    for (int i = 0; i < 3; ++i) {
        int f = i * NT + t;
        *(float4*)&out[VBASE + (size_t)n0 * 96 + f * 4] = *(const float4*)&sc[f * 4];
    }
}

extern "C" void kernel_launch(void* const* d_in, const int* in_sizes, int n_in,
                              void* d_out, int out_size, void* d_ws, size_t ws_size,
                              hipStream_t stream) {
    const float* s   = (const float*)d_in[0];
    const float* V   = (const float*)d_in[1];
    const float* Wh  = (const float*)d_in[2];
    const float* Wmu = (const float*)d_in[3];
    const float* Wmw = (const float*)d_in[4];
    const float* Wmb = (const float*)d_in[5];
    const float* Wgw = (const float*)d_in[6];
    const float* Wgb = (const float*)d_in[7];
    float* out = (float*)d_out;

    dim3 grid(NTOT / BN);   // 8192
    dim3 block(NT);         // 256

    if (ws_size >= 163840) {
        pack_w<<<320, 256, 0, stream>>>(Wmw, Wgw, (unsigned short*)d_ws);
        gvp_main<1><<<grid, block, 0, stream>>>(s, V, Wh, Wmu, Wmw, Wmb, Wgw, Wgb,
                                                (const unsigned short*)d_ws, out);
    } else {
        gvp_main<0><<<grid, block, 0, stream>>>(s, V, Wh, Wmu, Wmw, Wmb, Wgw, Wgb,
                                                nullptr, out);
    }
}